// Round 2
// baseline (2626.289 us; speedup 1.0000x reference)
//
#include <hip/hip_runtime.h>

// Shapes (hard-coded from reference): B=4, T=1024, C=16, D=256, P=4096
// Inputs (float32 unless noted): 0:x[B,T,C,D] 1:x_mask[B,T,C](u8 bool) 2:pos[B,T,C](i32)
// 3:pe[P,128,2] 4:wq_w[D,D] 5:wq_b[D] 6:wk_w 7:wk_b 8:wv_w 9:wv_b 10:ln_g 11:ln_b 12:ls_gamma
// Output: float32 [B,T,C,D]
// Workspace: q,k,v stored bf16 in [B*C,T,D] (3 x 32 MB). ls_gamma=1e-5 makes
// the attention path's bf16 rounding invisible (~1e-6 absolute in y).

typedef __attribute__((ext_vector_type(8))) short short8_t;
typedef __attribute__((ext_vector_type(8))) float float8_t;
typedef __attribute__((ext_vector_type(4))) float float4_t;

__device__ __forceinline__ float b2f(short s) {
    union { unsigned int u; float f; } x;
    x.u = ((unsigned int)(unsigned short)s) << 16;
    return x.f;
}
__device__ __forceinline__ short f2b(float f) {
    union { float f; unsigned int u; } x; x.f = f;
    unsigned int u = x.u;
    unsigned int r = (u + 0x7fffu + ((u >> 16) & 1u)) >> 16;
    return (short)r;
}
__device__ __forceinline__ void b2f8(const short8_t v, float* f) {
#pragma unroll
    for (int i = 0; i < 8; i++) f[i] = b2f(v[i]);
}

// ---------------------------------------------------------------------------
// Kernel A: QKV projection + rotary. 8 consecutive (b,t,c) rows per block.
// q,k,v written bf16 in [B*C, T, D] layout for attention locality.
// ---------------------------------------------------------------------------
__global__ __launch_bounds__(256) void qkv_rope_kernel(
    const float* __restrict__ x, const int* __restrict__ pos,
    const float* __restrict__ pe,
    const float* __restrict__ wq, const float* __restrict__ bq,
    const float* __restrict__ wk, const float* __restrict__ bk,
    const float* __restrict__ wv, const float* __restrict__ bv,
    short* __restrict__ qo, short* __restrict__ ko, short* __restrict__ vo)
{
    __shared__ __align__(16) float xs[8 * 256];  // 8 rows of x
    const int tid = threadIdx.x;
    const long row0 = (long)blockIdx.x * 8;

    {   // stage 8 contiguous rows (2048 floats)
        const float8_t* xp = (const float8_t*)(x + row0 * 256);
        float8_t v = xp[tid];
#pragma unroll
        for (int i = 0; i < 8; i++) xs[tid * 8 + i] = v[i];
    }
    __syncthreads();

    const int e = tid;
    float qa[8], ka[8], va[8];
#pragma unroll
    for (int r = 0; r < 8; r++) { qa[r] = 0.f; ka[r] = 0.f; va[r] = 0.f; }

    const float8_t* wqp = (const float8_t*)(wq + (long)e * 256);
    const float8_t* wkp = (const float8_t*)(wk + (long)e * 256);
    const float8_t* wvp = (const float8_t*)(wv + (long)e * 256);

    for (int d0 = 0; d0 < 32; d0++) {
        float8_t wqf = wqp[d0], wkf = wkp[d0], wvf = wvp[d0];
#pragma unroll
        for (int r = 0; r < 8; r++) {
            const float* xr = &xs[r * 256 + d0 * 8];
            float4_t x0 = *(const float4_t*)xr;
            float4_t x1 = *(const float4_t*)(xr + 4);
            float xv[8] = { x0.x, x0.y, x0.z, x0.w, x1.x, x1.y, x1.z, x1.w };
#pragma unroll
            for (int i = 0; i < 8; i++) {
                qa[r] += xv[i] * wqf[i];
                ka[r] += xv[i] * wkf[i];
                va[r] += xv[i] * wvf[i];
            }
        }
    }

    // bias (zeros in this problem, but apply for generality)
    const float bqf = bq[e], bkf = bk[e], bvf = bv[e];
#pragma unroll
    for (int r = 0; r < 8; r++) { qa[r] += bqf; ka[r] += bkf; va[r] += bvf; }

    // rotary: pair (2i, 2i+1) with (cos,sin) = pe[pos][i]
    const int half = e >> 1;
    const int odd = e & 1;
#pragma unroll
    for (int r = 0; r < 8; r++) {
        int pr = pos[row0 + r];
        const float* pp = pe + ((long)pr * 128 + half) * 2;
        float cc = pp[0], ss = pp[1];
        float s2 = odd ? ss : -ss;
        float qp = __shfl_xor(qa[r], 1);
        float kp = __shfl_xor(ka[r], 1);
        qa[r] = qa[r] * cc + qp * s2;
        ka[r] = ka[r] * cc + kp * s2;
    }

    // store in [B*C, T, D] as bf16
#pragma unroll
    for (int r = 0; r < 8; r++) {
        long row = row0 + r;
        int b = (int)(row >> 14);
        int t = (int)((row >> 4) & 1023);
        int c = (int)(row & 15);
        long o = (((long)(b * 16 + c)) * 1024 + t) * 256 + e;
        qo[o] = f2b(qa[r]);
        ko[o] = f2b(ka[r]);
        vo[o] = f2b(va[r]);
    }
}

// ---------------------------------------------------------------------------
// Kernel B: attention + epilogue. One block = 8 q-rows of one (b,c).
// ---------------------------------------------------------------------------
__global__ __launch_bounds__(256) void attn_kernel(
    const short* __restrict__ qg, const short* __restrict__ kg,
    const short* __restrict__ vg,
    const unsigned char* __restrict__ xmask, const float* __restrict__ x,
    const float* __restrict__ lsg, const float* __restrict__ lng,
    const float* __restrict__ lnb, float* __restrict__ out)
{
    __shared__ __align__(16) float qs[8 * 256];     // 8 KB
    __shared__ __align__(16) float sc[8][1024];     // 32 KB scores -> probs
    __shared__ __align__(16) short vst[32 * 256];   // 16 KB v staging
    __shared__ float redA[4], redB[4];

    const int tid = threadIdx.x;
    const int bid = blockIdx.x;
    const int bc = bid >> 7;            // 0..63
    const int tq0 = (bid & 127) * 8;
    const int b = bc >> 4, c = bc & 15;
    const long kvbase = (long)bc * 1024 * 256;

    {   // stage 8 q rows fp32
        const short8_t* qp = (const short8_t*)(qg + kvbase + (long)tq0 * 256);
        short8_t v = qp[tid];
#pragma unroll
        for (int i = 0; i < 8; i++) qs[tid * 8 + i] = b2f(v[i]);
    }
    __syncthreads();

    // ---- scores: thread handles k-rows {tid, tid+256, tid+512, tid+768} ----
    float acc[4][8];
#pragma unroll
    for (int j = 0; j < 4; j++)
#pragma unroll
        for (int r = 0; r < 8; r++) acc[j][r] = 0.f;

    const short8_t* kp0 = (const short8_t*)(kg + kvbase + (long)tid * 256);
    for (int e0 = 0; e0 < 32; e0++) {
        short8_t k0 = kp0[e0];
        short8_t k1 = kp0[e0 + 8192];
        short8_t k2 = kp0[e0 + 16384];
        short8_t k3 = kp0[e0 + 24576];
        float kf[4][8];
        b2f8(k0, kf[0]); b2f8(k1, kf[1]); b2f8(k2, kf[2]); b2f8(k3, kf[3]);
#pragma unroll
        for (int r = 0; r < 8; r++) {
            const float* qr = &qs[r * 256 + e0 * 8];
            float4_t q0 = *(const float4_t*)qr;
            float4_t q1 = *(const float4_t*)(qr + 4);
            float qv[8] = { q0.x, q0.y, q0.z, q0.w, q1.x, q1.y, q1.z, q1.w };
#pragma unroll
            for (int i = 0; i < 8; i++) {
                acc[0][r] += qv[i] * kf[0][i];
                acc[1][r] += qv[i] * kf[1][i];
                acc[2][r] += qv[i] * kf[2][i];
                acc[3][r] += qv[i] * kf[3][i];
            }
        }
    }
    const float scale = 0.0625f;  // 1/sqrt(256)
#pragma unroll
    for (int it = 0; it < 4; it++) {
        int kt = tid + it * 256;
        bool mk = xmask[((long)b * 1024 + kt) * 16 + c] != 0;
#pragma unroll
        for (int r = 0; r < 8; r++)
            sc[r][kt] = mk ? -1e30f : acc[it][r] * scale;
    }
    __syncthreads();

    // ---- softmax per q-row ----
    for (int r = 0; r < 8; r++) {
        float v0 = sc[r][tid], v1 = sc[r][tid + 256];
        float v2 = sc[r][tid + 512], v3 = sc[r][tid + 768];
        float m = fmaxf(fmaxf(v0, v1), fmaxf(v2, v3));
#pragma unroll
        for (int o = 1; o < 64; o <<= 1) m = fmaxf(m, __shfl_xor(m, o));
        if ((tid & 63) == 0) redA[tid >> 6] = m;
        __syncthreads();
        m = fmaxf(fmaxf(redA[0], redA[1]), fmaxf(redA[2], redA[3]));
        float e0 = __expf(v0 - m), e1 = __expf(v1 - m);
        float e2 = __expf(v2 - m), e3 = __expf(v3 - m);
        float s = e0 + e1 + e2 + e3;
#pragma unroll
        for (int o = 1; o < 64; o <<= 1) s += __shfl_xor(s, o);
        if ((tid & 63) == 0) redB[tid >> 6] = s;
        __syncthreads();
        s = redB[0] + redB[1] + redB[2] + redB[3];
        bool mq = xmask[((long)b * 1024 + tq0 + r) * 16 + c] != 0;
        float inv = mq ? 0.0f : (1.0f / s);   // masked q-row => p = 0 (ref nan_to_num rule)
        sc[r][tid] = e0 * inv;
        sc[r][tid + 256] = e1 * inv;
        sc[r][tid + 512] = e2 * inv;
        sc[r][tid + 768] = e3 * inv;
    }

    // ---- PV: group g (32 lanes) owns q-row g; thread owns 8 e's ----
    const int grp = tid >> 5, lane = tid & 31;
    const int eo = lane * 8;
    float oacc[8] = {0.f, 0.f, 0.f, 0.f, 0.f, 0.f, 0.f, 0.f};

    for (int t0 = 0; t0 < 1024; t0 += 32) {
        __syncthreads();   // protect vst reuse; first pass also fences sc writes
        const short8_t* vp = (const short8_t*)(vg + kvbase + (long)t0 * 256);
        short8_t* vs8 = (short8_t*)vst;
#pragma unroll
        for (int i = 0; i < 4; i++) vs8[tid + i * 256] = vp[tid + i * 256];
        __syncthreads();
#pragma unroll 4
        for (int t = 0; t < 32; t++) {
            float p = sc[grp][t0 + t];
            short8_t vv = *(const short8_t*)&vst[t * 256 + eo];
#pragma unroll
            for (int i = 0; i < 8; i++) oacc[i] += p * b2f(vv[i]);
        }
    }

    // ---- epilogue: y = x + ls_gamma * o ; LayerNorm(D=256) ; fp32 out ----
    const long xoff = (((long)b * 1024 + tq0 + grp) * 16 + c) * 256 + eo;
    float8_t xv = *(const float8_t*)(x + xoff);
    float8_t l8 = *(const float8_t*)(lsg + eo);
    float8_t g8 = *(const float8_t*)(lng + eo);
    float8_t bb = *(const float8_t*)(lnb + eo);
    float yv[8];
    float s1 = 0.f, s2 = 0.f;
#pragma unroll
    for (int i = 0; i < 8; i++) {
        yv[i] = xv[i] + l8[i] * oacc[i];
        s1 += yv[i];
        s2 += yv[i] * yv[i];
    }
#pragma unroll
    for (int o = 1; o < 32; o <<= 1) {
        s1 += __shfl_xor(s1, o);
        s2 += __shfl_xor(s2, o);
    }
    float mu = s1 * (1.0f / 256.0f);
    float var = s2 * (1.0f / 256.0f) - mu * mu;
    float rstd = rsqrtf(var + 1e-5f);
    float8_t o8;
#pragma unroll
    for (int i = 0; i < 8; i++)
        o8[i] = (yv[i] - mu) * rstd * g8[i] + bb[i];
    *(float8_t*)(out + xoff) = o8;
}

// ---------------------------------------------------------------------------
extern "C" void kernel_launch(void* const* d_in, const int* in_sizes, int n_in,
                              void* d_out, int out_size, void* d_ws, size_t ws_size,
                              hipStream_t stream) {
    const float* x = (const float*)d_in[0];
    const unsigned char* xmask = (const unsigned char*)d_in[1];
    const int* pos = (const int*)d_in[2];
    const float* pe = (const float*)d_in[3];
    const float* wq = (const float*)d_in[4];
    const float* bq = (const float*)d_in[5];
    const float* wk = (const float*)d_in[6];
    const float* bk = (const float*)d_in[7];
    const float* wv = (const float*)d_in[8];
    const float* bv = (const float*)d_in[9];
    const float* lng = (const float*)d_in[10];
    const float* lnb = (const float*)d_in[11];
    const float* lsg = (const float*)d_in[12];
    float* out = (float*)d_out;

    short* qw = (short*)d_ws;              // 3 x 32 MB bf16 scratch in d_ws
    short* kw = qw + 16777216;
    short* vw = kw + 16777216;

    qkv_rope_kernel<<<8192, 256, 0, stream>>>(x, pos, pe, wq, bq, wk, bk, wv, bv,
                                              qw, kw, vw);
    attn_kernel<<<8192, 256, 0, stream>>>(qw, kw, vw, xmask, x, lsg, lng, lnb, out);
}

// Round 3
// 2029.795 us; speedup vs baseline: 1.2939x; 1.2939x over previous
//
#include <hip/hip_runtime.h>

// B=4, T=1024, C=16, D=256, P=4096.  All float tensors fp32; x_mask u8; pos i32.
// ws: q[bc][t][d] bf16 (32MB) | k[bc][t][d] bf16 (32MB) | vt[bc][d][t] bf16 (32MB)

typedef __attribute__((ext_vector_type(8))) short short8_t;
typedef __attribute__((ext_vector_type(8))) float float8_t;
typedef __attribute__((ext_vector_type(4))) float float4_t;

__device__ __forceinline__ float b2f(short s) {
    union { unsigned int u; float f; } x;
    x.u = ((unsigned int)(unsigned short)s) << 16;
    return x.f;
}
__device__ __forceinline__ short f2b(float f) {
    union { float f; unsigned int u; } x; x.f = f;
    unsigned int u = x.u;
    return (short)((u + 0x7fffu + ((u >> 16) & 1u)) >> 16);
}
__device__ __forceinline__ void b2f8(const short8_t v, float* f) {
#pragma unroll
    for (int i = 0; i < 8; i++) f[i] = b2f(v[i]);
}

// ---------------------------------------------------------------------------
// Kernel A: QKV projection + rotary. Block = 8 t-rows of one (b,c).
// Q,K row-major [bc][t][d]; V transposed [bc][d][t] for MFMA B-frags.
// ---------------------------------------------------------------------------
__global__ __launch_bounds__(256) void qkv_rope_kernel(
    const float* __restrict__ x, const int* __restrict__ pos,
    const float* __restrict__ pe,
    const float* __restrict__ wq, const float* __restrict__ bq,
    const float* __restrict__ wk, const float* __restrict__ bk,
    const float* __restrict__ wv, const float* __restrict__ bv,
    short* __restrict__ qo, short* __restrict__ ko, short* __restrict__ vt)
{
    __shared__ __align__(16) float xs[8 * 256];
    const int tid = threadIdx.x;
    const int bc = blockIdx.x >> 7;
    const int t0 = (blockIdx.x & 127) * 8;
    const int b = bc >> 4, c = bc & 15;

    {   // stage 8 rows (t0..t0+7) of x for this (b,c)
        int r = tid >> 5, cc = (tid & 31) * 8;
        float8_t xv = *(const float8_t*)(x + (((long)b * 1024 + t0 + r) * 16 + c) * 256 + cc);
        *(float8_t*)&xs[r * 256 + cc] = xv;
    }
    __syncthreads();

    const int e = tid;
    float qa[8], ka[8], va[8];
#pragma unroll
    for (int r = 0; r < 8; r++) { qa[r] = 0.f; ka[r] = 0.f; va[r] = 0.f; }

    const float8_t* wqp = (const float8_t*)(wq + (long)e * 256);
    const float8_t* wkp = (const float8_t*)(wk + (long)e * 256);
    const float8_t* wvp = (const float8_t*)(wv + (long)e * 256);

    for (int d0 = 0; d0 < 32; d0++) {
        float8_t wqf = wqp[d0], wkf = wkp[d0], wvf = wvp[d0];
#pragma unroll
        for (int r = 0; r < 8; r++) {
            const float* xr = &xs[r * 256 + d0 * 8];
            float4_t x0 = *(const float4_t*)xr;
            float4_t x1 = *(const float4_t*)(xr + 4);
            float xv[8] = { x0.x, x0.y, x0.z, x0.w, x1.x, x1.y, x1.z, x1.w };
#pragma unroll
            for (int i = 0; i < 8; i++) {
                qa[r] += xv[i] * wqf[i];
                ka[r] += xv[i] * wkf[i];
                va[r] += xv[i] * wvf[i];
            }
        }
    }

    const float bqf = bq[e], bkf = bk[e], bvf = bv[e];
#pragma unroll
    for (int r = 0; r < 8; r++) { qa[r] += bqf; ka[r] += bkf; va[r] += bvf; }

    // rotary
    const int half = e >> 1;
    const int odd = e & 1;
#pragma unroll
    for (int r = 0; r < 8; r++) {
        int pr = pos[((long)b * 1024 + t0 + r) * 16 + c];
        const float* pp = pe + ((long)pr * 128 + half) * 2;
        float cc = pp[0], ss = pp[1];
        float s2 = odd ? ss : -ss;
        float qp = __shfl_xor(qa[r], 1);
        float kp = __shfl_xor(ka[r], 1);
        qa[r] = qa[r] * cc + qp * s2;
        ka[r] = ka[r] * cc + kp * s2;
    }

    // stores
    const long qkbase = (long)bc * 262144;
#pragma unroll
    for (int r = 0; r < 8; r++) {
        long o = qkbase + (long)(t0 + r) * 256 + e;
        qo[o] = f2b(qa[r]);
        ko[o] = f2b(ka[r]);
    }
    short8_t vv;
#pragma unroll
    for (int r = 0; r < 8; r++) vv[r] = f2b(va[r]);
    *(short8_t*)(vt + qkbase + (long)e * 1024 + t0) = vv;
}

// ---------------------------------------------------------------------------
// Kernel B: MFMA attention + fused LN epilogue. Block = 16 q-rows of one (b,c).
// 4 waves: phase1 each wave does 256 score-cols; phase2 each wave does 64 d's.
// ---------------------------------------------------------------------------
#define PST 1032   // LDS row stride (shorts) for P: +8 pad -> 2-way banks (free)

__global__ __launch_bounds__(256) void attn_kernel(
    const short* __restrict__ qg, const short* __restrict__ kg,
    const short* __restrict__ vt,
    const unsigned char* __restrict__ xmask, const float* __restrict__ x,
    const float* __restrict__ lsg, const float* __restrict__ lng,
    const float* __restrict__ lnb, float* __restrict__ out)
{
    __shared__ __align__(16) short ps[16 * PST];   // 33024 B; reused as fp32 O (stride 260)
    __shared__ float mbias[1024];

    const int tid = threadIdx.x;
    const int lane = tid & 63;
    const int wid = tid >> 6;
    const int bc = blockIdx.x >> 6;
    const int tq0 = (blockIdx.x & 63) * 16;
    const int b = bc >> 4, c = bc & 15;
    const long kvbase = (long)bc * 262144;
    const int row = lane & 15, quad = lane >> 4;

    // stage additive mask bias for this (b,c)
#pragma unroll
    for (int i = 0; i < 4; i++) {
        int t = tid * 4 + i;
        mbias[t] = xmask[((long)b * 1024 + t) * 16 + c] ? -1e30f : 0.0f;
    }

    // Q A-frags: A[m=row][k=quad*8+j], k-tile f covers d = f*32..f*32+31
    short8_t aq[8];
#pragma unroll
    for (int f = 0; f < 8; f++)
        aq[f] = *(const short8_t*)(qg + kvbase + (long)(tq0 + row) * 256 + f * 32 + quad * 8);

    __syncthreads();

    // ---- phase 1: S = QK^T (scaled, masked) -> ps bf16 ----
    const int c0 = wid * 256;
    const float scale = 0.0625f;   // 1/sqrt(256)
    short8_t bk0[8], bk1[8];
    auto loadK = [&](short8_t* bkf, int ct) {
        const short* kp = kg + kvbase + (long)(c0 + ct * 16 + row) * 256 + quad * 8;
#pragma unroll
        for (int f = 0; f < 8; f++) bkf[f] = *(const short8_t*)(kp + f * 32);
    };
    auto tile1 = [&](short8_t* bkf, int ct) {
        float4_t acc = {0.f, 0.f, 0.f, 0.f};
#pragma unroll
        for (int f = 0; f < 8; f++)
            acc = __builtin_amdgcn_mfma_f32_16x16x32_bf16(aq[f], bkf[f], acc, 0, 0, 0);
        int colt = c0 + ct * 16 + row;
        float mb = mbias[colt];
#pragma unroll
        for (int r = 0; r < 4; r++)
            ps[(quad * 4 + r) * PST + colt] = f2b(acc[r] * scale + mb);
    };
    loadK(bk0, 0);
#pragma unroll 1
    for (int ct = 0; ct < 16; ct += 2) {
        loadK(bk1, ct + 1);
        tile1(bk0, ct);
        if (ct + 2 < 16) loadK(bk0, ct + 2);
        tile1(bk1, ct + 1);
    }
    __syncthreads();

    // ---- softmax (each wave: 4 rows) ----
#pragma unroll 1
    for (int r8 = 0; r8 < 4; r8++) {
        int q = wid * 4 + r8;
        short8_t p0 = *(const short8_t*)&ps[q * PST + lane * 16];
        short8_t p1 = *(const short8_t*)&ps[q * PST + lane * 16 + 8];
        float v[16];
        b2f8(p0, v); b2f8(p1, v + 8);
        float m = v[0];
#pragma unroll
        for (int i = 1; i < 16; i++) m = fmaxf(m, v[i]);
#pragma unroll
        for (int o = 1; o < 64; o <<= 1) m = fmaxf(m, __shfl_xor(m, o));
        float s = 0.f;
#pragma unroll
        for (int i = 0; i < 16; i++) { v[i] = __expf(v[i] - m); s += v[i]; }
#pragma unroll
        for (int o = 1; o < 64; o <<= 1) s += __shfl_xor(s, o);
        bool mq = xmask[((long)b * 1024 + tq0 + q) * 16 + c] != 0;
        float inv = mq ? 0.f : (1.f / s);   // masked q-row => p=0 (ref nan_to_num)
        short8_t o0, o1;
#pragma unroll
        for (int i = 0; i < 8; i++) { o0[i] = f2b(v[i] * inv); o1[i] = f2b(v[i + 8] * inv); }
        *(short8_t*)&ps[q * PST + lane * 16] = o0;
        *(short8_t*)&ps[q * PST + lane * 16 + 8] = o1;
    }
    __syncthreads();

    // ---- phase 2: O = P V  (B-frags from vt[bc][d][t]) ----
    const int dh = wid * 64;
    float4_t oacc[4];
#pragma unroll
    for (int f = 0; f < 4; f++) oacc[f] = (float4_t){0.f, 0.f, 0.f, 0.f};
    short8_t bv0[4], bv1[4];
    auto loadV = [&](short8_t* bvf, int s) {
        const short* vp = vt + kvbase + (long)(dh + row) * 1024 + s * 32 + quad * 8;
#pragma unroll
        for (int f = 0; f < 4; f++) bvf[f] = *(const short8_t*)(vp + (long)f * 16 * 1024);
    };
    auto loadA = [&](int s) {
        return *(const short8_t*)&ps[row * PST + s * 32 + quad * 8];
    };
    short8_t apc = loadA(0);
    loadV(bv0, 0);
#pragma unroll 1
    for (int s = 0; s < 32; s += 2) {
        short8_t apn = loadA(s + 1);
        loadV(bv1, s + 1);
#pragma unroll
        for (int f = 0; f < 4; f++)
            oacc[f] = __builtin_amdgcn_mfma_f32_16x16x32_bf16(apc, bv0[f], oacc[f], 0, 0, 0);
        if (s + 2 < 32) { apc = loadA(s + 2); loadV(bv0, s + 2); }
#pragma unroll
        for (int f = 0; f < 4; f++)
            oacc[f] = __builtin_amdgcn_mfma_f32_16x16x32_bf16(apn, bv1[f], oacc[f], 0, 0, 0);
    }

    __syncthreads();               // everyone done reading ps
    float* os = (float*)ps;        // reuse as O fp32, stride 260
#pragma unroll
    for (int f = 0; f < 4; f++) {
        int d = dh + f * 16 + row;
#pragma unroll
        for (int r = 0; r < 4; r++)
            os[(quad * 4 + r) * 260 + d] = oacc[f][r];
    }
    __syncthreads();

    // ---- epilogue: y = x + ls_gamma*o ; LayerNorm ; fp32 out ----
    const int q = tid >> 4, d0 = (tid & 15) * 16;
    const long xoff = (((long)b * 1024 + tq0 + q) * 16 + c) * 256 + d0;
    float y[16];
    float s1 = 0.f, s2 = 0.f;
#pragma unroll
    for (int i = 0; i < 16; i += 8) {
        float8_t xv = *(const float8_t*)(x + xoff + i);
        float8_t g8 = *(const float8_t*)(lsg + d0 + i);
#pragma unroll
        for (int j = 0; j < 8; j++) {
            float yy = xv[j] + g8[j] * os[q * 260 + d0 + i + j];
            y[i + j] = yy; s1 += yy; s2 += yy * yy;
        }
    }
#pragma unroll
    for (int o = 1; o < 16; o <<= 1) { s1 += __shfl_xor(s1, o); s2 += __shfl_xor(s2, o); }
    float mu = s1 * (1.f / 256.f);
    float var = s2 * (1.f / 256.f) - mu * mu;
    float rstd = rsqrtf(var + 1e-5f);
#pragma unroll
    for (int i = 0; i < 16; i += 8) {
        float8_t g8 = *(const float8_t*)(lng + d0 + i);
        float8_t b8 = *(const float8_t*)(lnb + d0 + i);
        float8_t o8;
#pragma unroll
        for (int j = 0; j < 8; j++) o8[j] = (y[i + j] - mu) * rstd * g8[j] + b8[j];
        *(float8_t*)(out + xoff + i) = o8;
    }
}

// ---------------------------------------------------------------------------
extern "C" void kernel_launch(void* const* d_in, const int* in_sizes, int n_in,
                              void* d_out, int out_size, void* d_ws, size_t ws_size,
                              hipStream_t stream) {
    const float* x = (const float*)d_in[0];
    const unsigned char* xmask = (const unsigned char*)d_in[1];
    const int* pos = (const int*)d_in[2];
    const float* pe = (const float*)d_in[3];
    const float* wq = (const float*)d_in[4];
    const float* bq = (const float*)d_in[5];
    const float* wk = (const float*)d_in[6];
    const float* bk = (const float*)d_in[7];
    const float* wv = (const float*)d_in[8];
    const float* bv = (const float*)d_in[9];
    const float* lng = (const float*)d_in[10];
    const float* lnb = (const float*)d_in[11];
    const float* lsg = (const float*)d_in[12];
    float* out = (float*)d_out;

    short* qw = (short*)d_ws;
    short* kw = qw + 16777216;
    short* vtw = kw + 16777216;

    qkv_rope_kernel<<<8192, 256, 0, stream>>>(x, pos, pe, wq, bq, wk, bk, wv, bv,
                                              qw, kw, vtw);
    attn_kernel<<<4096, 256, 0, stream>>>(qw, kw, vtw, xmask, x, lsg, lng, lnb, out);
}

// Round 4
// 717.580 us; speedup vs baseline: 3.6599x; 2.8287x over previous
//
#include <hip/hip_runtime.h>

// B=4, T=1024, C=16, D=256, P=4096.  Float tensors fp32; x_mask u8; pos i32.
// ws layout: q[bc][t][d] bf16 (32MB) | k[bc][t][d] bf16 (32MB) | vt[bc][d][t] bf16 (32MB)
//            | wb[3][256][256] bf16 (384KB)

typedef __attribute__((ext_vector_type(8))) short short8_t;
typedef __attribute__((ext_vector_type(4))) short short4_t;
typedef __attribute__((ext_vector_type(8))) float float8_t;
typedef __attribute__((ext_vector_type(4))) float float4_t;
typedef __attribute__((ext_vector_type(2))) float float2_t;

__device__ __forceinline__ float b2f(short s) {
    union { unsigned int u; float f; } x;
    x.u = ((unsigned int)(unsigned short)s) << 16;
    return x.f;
}
__device__ __forceinline__ short f2b(float f) {           // round-to-nearest
    union { float f; unsigned int u; } x; x.f = f;
    unsigned int u = x.u;
    return (short)((u + 0x7fffu + ((u >> 16) & 1u)) >> 16);
}
__device__ __forceinline__ short f2bt(float f) {          // truncate (cheap; plenty of headroom)
    union { float f; unsigned int u; } x; x.f = f;
    return (short)(x.u >> 16);
}
__device__ __forceinline__ void b2f8(const short8_t v, float* f) {
#pragma unroll
    for (int i = 0; i < 8; i++) f[i] = b2f(v[i]);
}

// ---------------------------------------------------------------------------
// Kernel 0: convert wq|wk|wv fp32 -> bf16 (trunc) into wb. 192 blocks x 256.
// ---------------------------------------------------------------------------
__global__ __launch_bounds__(256) void wconv_kernel(
    const float* __restrict__ wq, const float* __restrict__ wk,
    const float* __restrict__ wv, short* __restrict__ wb)
{
    int idx = blockIdx.x * 256 + threadIdx.x;   // 0..49151, 16384 float4 per matrix
    int mat = idx >> 14;
    int off = idx & 16383;
    const float* src = (mat == 0) ? wq : ((mat == 1) ? wk : wv);
    float4_t v = *(const float4_t*)(src + (long)off * 4);
    short4_t o;
#pragma unroll
    for (int j = 0; j < 4; j++) o[j] = f2bt(v[j]);
    *(short4_t*)(wb + (long)idx * 4) = o;
}

// ---------------------------------------------------------------------------
// Kernel 1: MFMA QKV projection + rotary. Block = 64 t-rows of one (b,c).
// Wave w computes feature-slice n0=w*64 for all 64 rows (16 mfma tiles/matrix).
// Q,K stored row-major [bc][t][d]; V stored transposed [bc][d][t].
// ---------------------------------------------------------------------------
__global__ __launch_bounds__(256) void qkv_mfma_kernel(
    const float* __restrict__ x, const int* __restrict__ pos,
    const float* __restrict__ pe, const short* __restrict__ wb,
    const float* __restrict__ bq, const float* __restrict__ bk,
    const float* __restrict__ bv,
    short* __restrict__ qo, short* __restrict__ ko, short* __restrict__ vt)
{
    __shared__ __align__(16) short xs[64 * 264];   // x tile bf16, padded stride
    __shared__ __align__(16) short ys[18432];      // q/k: [64][264]; v: [256][72]
    __shared__ int posb[64];

    const int tid = threadIdx.x;
    const int lane = tid & 63;
    const int wid = tid >> 6;
    const int bc = blockIdx.x >> 4;
    const int t0 = (blockIdx.x & 15) * 64;
    const int b = bc >> 4, c = bc & 15;
    const int row = lane & 15, quad = lane >> 4;
    const int odd = lane & 1;
    const int n0 = wid * 64;
    const long kvbase = (long)bc * 262144;

    // ---- stage x tile (fp32 -> bf16 trunc), 512B-contiguous global reads ----
#pragma unroll
    for (int j = 0; j < 8; j++) {
        int idx = tid + j * 256;
        int r = idx >> 5, c8 = idx & 31;
        const float* xp = x + (((long)b * 1024 + t0 + r) * 16 + c) * 256 + c8 * 8;
        float4_t a = *(const float4_t*)xp;
        float4_t d = *(const float4_t*)(xp + 4);
        short8_t o;
        o[0] = f2bt(a.x); o[1] = f2bt(a.y); o[2] = f2bt(a.z); o[3] = f2bt(a.w);
        o[4] = f2bt(d.x); o[5] = f2bt(d.y); o[6] = f2bt(d.z); o[7] = f2bt(d.w);
        *(short8_t*)&xs[r * 264 + c8 * 8] = o;
    }
    if (tid < 64) posb[tid] = pos[((long)b * 1024 + t0 + tid) * 16 + c];
    __syncthreads();

#pragma unroll 1
    for (int mat = 0; mat < 3; mat++) {
        const short* W = wb + mat * 65536;
        float4_t acc[4][4];
#pragma unroll
        for (int mt = 0; mt < 4; mt++)
#pragma unroll
            for (int nt = 0; nt < 4; nt++) acc[mt][nt] = (float4_t){0.f, 0.f, 0.f, 0.f};

        short8_t Ac[4], Bc[4], An[4], Bn[4];
        auto loadA = [&](short8_t* A, int k0) {
#pragma unroll
            for (int mt = 0; mt < 4; mt++)
                A[mt] = *(const short8_t*)&xs[(mt * 16 + row) * 264 + k0 * 32 + quad * 8];
        };
        auto loadB = [&](short8_t* Bf, int k0) {
#pragma unroll
            for (int nt = 0; nt < 4; nt++)
                Bf[nt] = *(const short8_t*)(W + (n0 + nt * 16 + row) * 256 + k0 * 32 + quad * 8);
        };
        loadA(Ac, 0); loadB(Bc, 0);
#pragma unroll
        for (int k0 = 0; k0 < 8; k0++) {
            if (k0 < 7) { loadA(An, k0 + 1); loadB(Bn, k0 + 1); }
#pragma unroll
            for (int mt = 0; mt < 4; mt++)
#pragma unroll
                for (int nt = 0; nt < 4; nt++)
                    acc[mt][nt] = __builtin_amdgcn_mfma_f32_16x16x32_bf16(
                        Ac[mt], Bc[nt], acc[mt][nt], 0, 0, 0);
            if (k0 < 7) {
#pragma unroll
                for (int i = 0; i < 4; i++) { Ac[i] = An[i]; Bc[i] = Bn[i]; }
            }
        }

        // ---- bias ----
        const float* bias = (mat == 0) ? bq : ((mat == 1) ? bk : bv);
        float bs[4];
#pragma unroll
        for (int nt = 0; nt < 4; nt++) bs[nt] = bias[n0 + nt * 16 + row];
#pragma unroll
        for (int mt = 0; mt < 4; mt++)
#pragma unroll
            for (int nt = 0; nt < 4; nt++)
#pragma unroll
                for (int r = 0; r < 4; r++) acc[mt][nt][r] += bs[nt];

        // ---- rotary (q,k only): features pair across adjacent lanes ----
        if (mat < 2) {
#pragma unroll
            for (int mt = 0; mt < 4; mt++)
#pragma unroll
                for (int r = 0; r < 4; r++) {
                    int p = posb[mt * 16 + quad * 4 + r];
                    const float* pb = pe + (long)p * 256;
#pragma unroll
                    for (int nt = 0; nt < 4; nt++) {
                        int i = (n0 + nt * 16 + row) >> 1;
                        float2_t cs = *(const float2_t*)(pb + i * 2);
                        float v = acc[mt][nt][r];
                        float pr = __shfl_xor(v, 1);
                        acc[mt][nt][r] = v * cs.x + pr * (odd ? cs.y : -cs.y);
                    }
                }
        }

        // ---- store via LDS so all global writes are >=128B contiguous ----
        __syncthreads();   // previous matrix's ys readers are done
        if (mat < 2) {
#pragma unroll
            for (int mt = 0; mt < 4; mt++)
#pragma unroll
                for (int nt = 0; nt < 4; nt++) {
                    int n = n0 + nt * 16 + row;
#pragma unroll
                    for (int r = 0; r < 4; r++)
                        ys[(mt * 16 + quad * 4 + r) * 264 + n] = f2bt(acc[mt][nt][r]);
                }
            __syncthreads();
            short* dst = ((mat == 0) ? qo : ko) + kvbase + (long)t0 * 256;
#pragma unroll
            for (int j = 0; j < 8; j++) {
                int idx = tid + j * 256;
                int r = idx >> 5, c8 = idx & 31;
                *(short8_t*)(dst + r * 256 + c8 * 8) = *(const short8_t*)&ys[r * 264 + c8 * 8];
            }
        } else {
            // transpose in LDS: ys_t[n][m], stride 72
#pragma unroll
            for (int mt = 0; mt < 4; mt++)
#pragma unroll
                for (int nt = 0; nt < 4; nt++) {
                    int n = n0 + nt * 16 + row;
                    short4_t o4;
#pragma unroll
                    for (int r = 0; r < 4; r++) o4[r] = f2bt(acc[mt][nt][r]);
                    *(short4_t*)&ys[n * 72 + mt * 16 + quad * 4] = o4;
                }
            __syncthreads();
#pragma unroll
            for (int j = 0; j < 8; j++) {
                int idx = tid + j * 256;
                int d = idx >> 3, t8 = idx & 7;
                *(short8_t*)(vt + kvbase + (long)d * 1024 + t0 + t8 * 8) =
                    *(const short8_t*)&ys[d * 72 + t8 * 8];
            }
        }
    }
}

// ---------------------------------------------------------------------------
// Kernel 2: MFMA attention + fused LN epilogue (unchanged from R3).
// ---------------------------------------------------------------------------
#define PST 1032

__global__ __launch_bounds__(256) void attn_kernel(
    const short* __restrict__ qg, const short* __restrict__ kg,
    const short* __restrict__ vt,
    const unsigned char* __restrict__ xmask, const float* __restrict__ x,
    const float* __restrict__ lsg, const float* __restrict__ lng,
    const float* __restrict__ lnb, float* __restrict__ out)
{
    __shared__ __align__(16) short ps[16 * PST];
    __shared__ float mbias[1024];

    const int tid = threadIdx.x;
    const int lane = tid & 63;
    const int wid = tid >> 6;
    const int bc = blockIdx.x >> 6;
    const int tq0 = (blockIdx.x & 63) * 16;
    const int b = bc >> 4, c = bc & 15;
    const long kvbase = (long)bc * 262144;
    const int row = lane & 15, quad = lane >> 4;

#pragma unroll
    for (int i = 0; i < 4; i++) {
        int t = tid * 4 + i;
        mbias[t] = xmask[((long)b * 1024 + t) * 16 + c] ? -1e30f : 0.0f;
    }

    short8_t aq[8];
#pragma unroll
    for (int f = 0; f < 8; f++)
        aq[f] = *(const short8_t*)(qg + kvbase + (long)(tq0 + row) * 256 + f * 32 + quad * 8);

    __syncthreads();

    const int c0 = wid * 256;
    const float scale = 0.0625f;
    short8_t bk0[8], bk1[8];
    auto loadK = [&](short8_t* bkf, int ct) {
        const short* kp = kg + kvbase + (long)(c0 + ct * 16 + row) * 256 + quad * 8;
#pragma unroll
        for (int f = 0; f < 8; f++) bkf[f] = *(const short8_t*)(kp + f * 32);
    };
    auto tile1 = [&](short8_t* bkf, int ct) {
        float4_t acc = {0.f, 0.f, 0.f, 0.f};
#pragma unroll
        for (int f = 0; f < 8; f++)
            acc = __builtin_amdgcn_mfma_f32_16x16x32_bf16(aq[f], bkf[f], acc, 0, 0, 0);
        int colt = c0 + ct * 16 + row;
        float mb = mbias[colt];
#pragma unroll
        for (int r = 0; r < 4; r++)
            ps[(quad * 4 + r) * PST + colt] = f2b(acc[r] * scale + mb);
    };
    loadK(bk0, 0);
#pragma unroll 1
    for (int ct = 0; ct < 16; ct += 2) {
        loadK(bk1, ct + 1);
        tile1(bk0, ct);
        if (ct + 2 < 16) loadK(bk0, ct + 2);
        tile1(bk1, ct + 1);
    }
    __syncthreads();

#pragma unroll 1
    for (int r8 = 0; r8 < 4; r8++) {
        int q = wid * 4 + r8;
        short8_t p0 = *(const short8_t*)&ps[q * PST + lane * 16];
        short8_t p1 = *(const short8_t*)&ps[q * PST + lane * 16 + 8];
        float v[16];
        b2f8(p0, v); b2f8(p1, v + 8);
        float m = v[0];
#pragma unroll
        for (int i = 1; i < 16; i++) m = fmaxf(m, v[i]);
#pragma unroll
        for (int o = 1; o < 64; o <<= 1) m = fmaxf(m, __shfl_xor(m, o));
        float s = 0.f;
#pragma unroll
        for (int i = 0; i < 16; i++) { v[i] = __expf(v[i] - m); s += v[i]; }
#pragma unroll
        for (int o = 1; o < 64; o <<= 1) s += __shfl_xor(s, o);
        bool mq = xmask[((long)b * 1024 + tq0 + q) * 16 + c] != 0;
        float inv = mq ? 0.f : (1.f / s);
        short8_t o0, o1;
#pragma unroll
        for (int i = 0; i < 8; i++) { o0[i] = f2b(v[i] * inv); o1[i] = f2b(v[i + 8] * inv); }
        *(short8_t*)&ps[q * PST + lane * 16] = o0;
        *(short8_t*)&ps[q * PST + lane * 16 + 8] = o1;
    }
    __syncthreads();

    const int dh = wid * 64;
    float4_t oacc[4];
#pragma unroll
    for (int f = 0; f < 4; f++) oacc[f] = (float4_t){0.f, 0.f, 0.f, 0.f};
    short8_t bv0[4], bv1[4];
    auto loadV = [&](short8_t* bvf, int s) {
        const short* vp = vt + kvbase + (long)(dh + row) * 1024 + s * 32 + quad * 8;
#pragma unroll
        for (int f = 0; f < 4; f++) bvf[f] = *(const short8_t*)(vp + (long)f * 16 * 1024);
    };
    auto loadA = [&](int s) {
        return *(const short8_t*)&ps[row * PST + s * 32 + quad * 8];
    };
    short8_t apc = loadA(0);
    loadV(bv0, 0);
#pragma unroll 1
    for (int s = 0; s < 32; s += 2) {
        short8_t apn = loadA(s + 1);
        loadV(bv1, s + 1);
#pragma unroll
        for (int f = 0; f < 4; f++)
            oacc[f] = __builtin_amdgcn_mfma_f32_16x16x32_bf16(apc, bv0[f], oacc[f], 0, 0, 0);
        if (s + 2 < 32) { apc = loadA(s + 2); loadV(bv0, s + 2); }
#pragma unroll
        for (int f = 0; f < 4; f++)
            oacc[f] = __builtin_amdgcn_mfma_f32_16x16x32_bf16(apn, bv1[f], oacc[f], 0, 0, 0);
    }

    __syncthreads();
    float* os = (float*)ps;
#pragma unroll
    for (int f = 0; f < 4; f++) {
        int d = dh + f * 16 + row;
#pragma unroll
        for (int r = 0; r < 4; r++)
            os[(quad * 4 + r) * 260 + d] = oacc[f][r];
    }
    __syncthreads();

    const int q = tid >> 4, d0 = (tid & 15) * 16;
    const long xoff = (((long)b * 1024 + tq0 + q) * 16 + c) * 256 + d0;
    float y[16];
    float s1 = 0.f, s2 = 0.f;
#pragma unroll
    for (int i = 0; i < 16; i += 8) {
        float8_t xv = *(const float8_t*)(x + xoff + i);
        float8_t g8 = *(const float8_t*)(lsg + d0 + i);
#pragma unroll
        for (int j = 0; j < 8; j++) {
            float yy = xv[j] + g8[j] * os[q * 260 + d0 + i + j];
            y[i + j] = yy; s1 += yy; s2 += yy * yy;
        }
    }
#pragma unroll
    for (int o = 1; o < 16; o <<= 1) { s1 += __shfl_xor(s1, o); s2 += __shfl_xor(s2, o); }
    float mu = s1 * (1.f / 256.f);
    float var = s2 * (1.f / 256.f) - mu * mu;
    float rstd = rsqrtf(var + 1e-5f);
#pragma unroll
    for (int i = 0; i < 16; i += 8) {
        float8_t g8 = *(const float8_t*)(lng + d0 + i);
        float8_t b8 = *(const float8_t*)(lnb + d0 + i);
        float8_t o8;
#pragma unroll
        for (int j = 0; j < 8; j++) o8[j] = (y[i + j] - mu) * rstd * g8[j] + b8[j];
        *(float8_t*)(out + xoff + i) = o8;
    }
}

// ---------------------------------------------------------------------------
extern "C" void kernel_launch(void* const* d_in, const int* in_sizes, int n_in,
                              void* d_out, int out_size, void* d_ws, size_t ws_size,
                              hipStream_t stream) {
    const float* x = (const float*)d_in[0];
    const unsigned char* xmask = (const unsigned char*)d_in[1];
    const int* pos = (const int*)d_in[2];
    const float* pe = (const float*)d_in[3];
    const float* wq = (const float*)d_in[4];
    const float* bq = (const float*)d_in[5];
    const float* wk = (const float*)d_in[6];
    const float* bk = (const float*)d_in[7];
    const float* wv = (const float*)d_in[8];
    const float* bv = (const float*)d_in[9];
    const float* lng = (const float*)d_in[10];
    const float* lnb = (const float*)d_in[11];
    const float* lsg = (const float*)d_in[12];
    float* out = (float*)d_out;

    short* qw = (short*)d_ws;              // 32MB
    short* kw = qw + 16777216;             // 32MB
    short* vtw = kw + 16777216;            // 32MB
    short* wbw = vtw + 16777216;           // 384KB bf16 weights

    wconv_kernel<<<192, 256, 0, stream>>>(wq, wk, wv, wbw);
    qkv_mfma_kernel<<<1024, 256, 0, stream>>>(x, pos, pe, wbw, bq, bk, bv,
                                              qw, kw, vtw);
    attn_kernel<<<4096, 256, 0, stream>>>(qw, kw, vtw, xmask, x, lsg, lng, lnb, out);
}

// Round 5
// 502.106 us; speedup vs baseline: 5.2305x; 1.4291x over previous
//
#include <hip/hip_runtime.h>

// B=4, T=1024, C=16, D=256, P=4096.  Float tensors fp32; x_mask u8; pos i32.
// ws: q[bc][t][d] bf16 32MB | k[bc][t][d] bf16 32MB | vt[bc][d][t] bf16 32MB
//     | wb[3][256][256] bf16 384KB | mbg[64][1024] f32 256KB

typedef __attribute__((ext_vector_type(8))) short short8_t;
typedef __attribute__((ext_vector_type(4))) short short4_t;
typedef __attribute__((ext_vector_type(8))) float float8_t;
typedef __attribute__((ext_vector_type(4))) float float4_t;
typedef __attribute__((ext_vector_type(2))) float float2_t;

__device__ __forceinline__ float b2f(short s) {
    union { unsigned int u; float f; } x;
    x.u = ((unsigned int)(unsigned short)s) << 16;
    return x.f;
}
__device__ __forceinline__ short f2bt(float f) {   // truncate: ample headroom here
    union { float f; unsigned int u; } x; x.f = f;
    return (short)(x.u >> 16);
}
__device__ __forceinline__ void b2f8(const short8_t v, float* f) {
#pragma unroll
    for (int i = 0; i < 8; i++) f[i] = b2f(v[i]);
}
// XOR-swizzled score LDS addressing (stride 1024 shorts, 64KB total).
// Rows r and r+8 share banks -> only 2-way aliasing (free on CDNA4).
__device__ __forceinline__ int swz(int r, int cs) {       // scalar short index
    return r * 1024 + (((cs >> 1) ^ ((r & 7) << 2)) << 1) + (cs & 1);
}
__device__ __forceinline__ int swz8(int r, int cs) {      // 8-short-aligned base
    return r * 1024 + (((cs >> 1) ^ ((r & 7) << 2)) << 1);
}

// ---------------------------------------------------------------------------
// Kernel 0: weights fp32->bf16 + mask-bias table. 448 blocks x 256.
// ---------------------------------------------------------------------------
__global__ __launch_bounds__(256) void prep_kernel(
    const float* __restrict__ wq, const float* __restrict__ wk,
    const float* __restrict__ wv, const unsigned char* __restrict__ xmask,
    short* __restrict__ wb, float* __restrict__ mbg)
{
    if (blockIdx.x < 192) {
        int idx = blockIdx.x * 256 + threadIdx.x;
        int mat = idx >> 14, off = idx & 16383;
        const float* src = (mat == 0) ? wq : ((mat == 1) ? wk : wv);
        float4_t v = *(const float4_t*)(src + (long)off * 4);
        short4_t o;
#pragma unroll
        for (int j = 0; j < 4; j++) o[j] = f2bt(v[j]);
        *(short4_t*)(wb + (long)idx * 4) = o;
    } else {
        int idx = (blockIdx.x - 192) * 256 + threadIdx.x;   // 0..65535
        int bc = idx >> 10, t = idx & 1023;
        int b = bc >> 4, c = bc & 15;
        mbg[idx] = xmask[((long)b * 1024 + t) * 16 + c] ? -1e30f : 0.0f;
    }
}

// ---------------------------------------------------------------------------
// Kernel 1: MFMA QKV projection + rotary (unchanged from R4).
// ---------------------------------------------------------------------------
__global__ __launch_bounds__(256) void qkv_mfma_kernel(
    const float* __restrict__ x, const int* __restrict__ pos,
    const float* __restrict__ pe, const short* __restrict__ wb,
    const float* __restrict__ bq, const float* __restrict__ bk,
    const float* __restrict__ bv,
    short* __restrict__ qo, short* __restrict__ ko, short* __restrict__ vt)
{
    __shared__ __align__(16) short xs[64 * 264];
    __shared__ __align__(16) short ys[18432];
    __shared__ int posb[64];

    const int tid = threadIdx.x;
    const int lane = tid & 63;
    const int wid = tid >> 6;
    const int bc = blockIdx.x >> 4;
    const int t0 = (blockIdx.x & 15) * 64;
    const int b = bc >> 4, c = bc & 15;
    const int row = lane & 15, quad = lane >> 4;
    const int odd = lane & 1;
    const int n0 = wid * 64;
    const long kvbase = (long)bc * 262144;

#pragma unroll
    for (int j = 0; j < 8; j++) {
        int idx = tid + j * 256;
        int r = idx >> 5, c8 = idx & 31;
        const float* xp = x + (((long)b * 1024 + t0 + r) * 16 + c) * 256 + c8 * 8;
        float4_t a = *(const float4_t*)xp;
        float4_t d = *(const float4_t*)(xp + 4);
        short8_t o;
        o[0] = f2bt(a.x); o[1] = f2bt(a.y); o[2] = f2bt(a.z); o[3] = f2bt(a.w);
        o[4] = f2bt(d.x); o[5] = f2bt(d.y); o[6] = f2bt(d.z); o[7] = f2bt(d.w);
        *(short8_t*)&xs[r * 264 + c8 * 8] = o;
    }
    if (tid < 64) posb[tid] = pos[((long)b * 1024 + t0 + tid) * 16 + c];
    __syncthreads();

#pragma unroll 1
    for (int mat = 0; mat < 3; mat++) {
        const short* W = wb + mat * 65536;
        float4_t acc[4][4];
#pragma unroll
        for (int mt = 0; mt < 4; mt++)
#pragma unroll
            for (int nt = 0; nt < 4; nt++) acc[mt][nt] = (float4_t){0.f, 0.f, 0.f, 0.f};

        short8_t Ac[4], Bc[4], An[4], Bn[4];
        auto loadA = [&](short8_t* A, int k0) {
#pragma unroll
            for (int mt = 0; mt < 4; mt++)
                A[mt] = *(const short8_t*)&xs[(mt * 16 + row) * 264 + k0 * 32 + quad * 8];
        };
        auto loadB = [&](short8_t* Bf, int k0) {
#pragma unroll
            for (int nt = 0; nt < 4; nt++)
                Bf[nt] = *(const short8_t*)(W + (n0 + nt * 16 + row) * 256 + k0 * 32 + quad * 8);
        };
        loadA(Ac, 0); loadB(Bc, 0);
#pragma unroll
        for (int k0 = 0; k0 < 8; k0++) {
            if (k0 < 7) { loadA(An, k0 + 1); loadB(Bn, k0 + 1); }
#pragma unroll
            for (int mt = 0; mt < 4; mt++)
#pragma unroll
                for (int nt = 0; nt < 4; nt++)
                    acc[mt][nt] = __builtin_amdgcn_mfma_f32_16x16x32_bf16(
                        Ac[mt], Bc[nt], acc[mt][nt], 0, 0, 0);
            if (k0 < 7) {
#pragma unroll
                for (int i = 0; i < 4; i++) { Ac[i] = An[i]; Bc[i] = Bn[i]; }
            }
        }

        const float* bias = (mat == 0) ? bq : ((mat == 1) ? bk : bv);
        float bs[4];
#pragma unroll
        for (int nt = 0; nt < 4; nt++) bs[nt] = bias[n0 + nt * 16 + row];
#pragma unroll
        for (int mt = 0; mt < 4; mt++)
#pragma unroll
            for (int nt = 0; nt < 4; nt++)
#pragma unroll
                for (int r = 0; r < 4; r++) acc[mt][nt][r] += bs[nt];

        if (mat < 2) {
#pragma unroll
            for (int mt = 0; mt < 4; mt++)
#pragma unroll
                for (int r = 0; r < 4; r++) {
                    int p = posb[mt * 16 + quad * 4 + r];
                    const float* pb = pe + (long)p * 256;
#pragma unroll
                    for (int nt = 0; nt < 4; nt++) {
                        int i = (n0 + nt * 16 + row) >> 1;
                        float2_t cs = *(const float2_t*)(pb + i * 2);
                        float v = acc[mt][nt][r];
                        float pr = __shfl_xor(v, 1);
                        acc[mt][nt][r] = v * cs.x + pr * (odd ? cs.y : -cs.y);
                    }
                }
        }

        __syncthreads();
        if (mat < 2) {
#pragma unroll
            for (int mt = 0; mt < 4; mt++)
#pragma unroll
                for (int nt = 0; nt < 4; nt++) {
                    int n = n0 + nt * 16 + row;
#pragma unroll
                    for (int r = 0; r < 4; r++)
                        ys[(mt * 16 + quad * 4 + r) * 264 + n] = f2bt(acc[mt][nt][r]);
                }
            __syncthreads();
            short* dst = ((mat == 0) ? qo : ko) + kvbase + (long)t0 * 256;
#pragma unroll
            for (int j = 0; j < 8; j++) {
                int idx = tid + j * 256;
                int r = idx >> 5, c8 = idx & 31;
                *(short8_t*)(dst + r * 256 + c8 * 8) = *(const short8_t*)&ys[r * 264 + c8 * 8];
            }
        } else {
#pragma unroll
            for (int mt = 0; mt < 4; mt++)
#pragma unroll
                for (int nt = 0; nt < 4; nt++) {
                    int n = n0 + nt * 16 + row;
                    short4_t o4;
#pragma unroll
                    for (int r = 0; r < 4; r++) o4[r] = f2bt(acc[mt][nt][r]);
                    *(short4_t*)&ys[n * 72 + mt * 16 + quad * 4] = o4;
                }
            __syncthreads();
#pragma unroll
            for (int j = 0; j < 8; j++) {
                int idx = tid + j * 256;
                int d = idx >> 3, t8 = idx & 7;
                *(short8_t*)(vt + kvbase + (long)d * 1024 + t0 + t8 * 8) =
                    *(const short8_t*)&ys[d * 72 + t8 * 8];
            }
        }
    }
}

// ---------------------------------------------------------------------------
// Kernel 2: MFMA attention, 32 q-rows/block, prefetch-2, swizzled 64KB LDS.
// ---------------------------------------------------------------------------
__global__ __launch_bounds__(256) void attn_kernel(
    const short* __restrict__ qg, const short* __restrict__ kg,
    const short* __restrict__ vt, const float* __restrict__ mbg,
    const float* __restrict__ x,
    const float* __restrict__ lsg, const float* __restrict__ lng,
    const float* __restrict__ lnb, float* __restrict__ out)
{
    __shared__ __align__(16) short ps[32 * 1024];   // 64KB; reused as fp32 O[32][260]

    const int tid = threadIdx.x;
    const int lane = tid & 63;
    const int wid = tid >> 6;
    const int bc = blockIdx.x >> 5;
    const int tq0 = (blockIdx.x & 31) * 32;
    const int b = bc >> 4, c = bc & 15;
    const long kvbase = (long)bc * 262144;
    const int bcq = bc * 1024;
    const int row = lane & 15, quad = lane >> 4;

    // Q A-frags: 2 m-tiles x 8 k-frags
    short8_t aq[2][8];
#pragma unroll
    for (int mt = 0; mt < 2; mt++)
#pragma unroll
        for (int f = 0; f < 8; f++)
            aq[mt][f] = *(const short8_t*)(qg + kvbase +
                (long)(tq0 + mt * 16 + row) * 256 + f * 32 + quad * 8);

    // ---- phase 1: S = QK^T (scaled, mask-biased) -> ps bf16 (swizzled) ----
    const int c0 = wid * 256;
    const float scale = 0.0625f;
    short8_t kb[3][8];
    auto loadK = [&](short8_t* dst, int ct) {
        const short* kp = kg + kvbase + (long)(c0 + ct * 16 + row) * 256 + quad * 8;
#pragma unroll
        for (int f = 0; f < 8; f++) dst[f] = *(const short8_t*)(kp + f * 32);
    };
    auto tileS = [&](short8_t* kf, int ct) {
        int colt = c0 + ct * 16 + row;
        float mb = mbg[bcq + colt];
#pragma unroll
        for (int mt = 0; mt < 2; mt++) {
            float4_t acc = {0.f, 0.f, 0.f, 0.f};
#pragma unroll
            for (int f = 0; f < 8; f++)
                acc = __builtin_amdgcn_mfma_f32_16x16x32_bf16(aq[mt][f], kf[f], acc, 0, 0, 0);
#pragma unroll
            for (int r = 0; r < 4; r++)
                ps[swz(mt * 16 + quad * 4 + r, colt)] = f2bt(acc[r] * scale + mb);
        }
    };
    loadK(kb[0], 0); loadK(kb[1], 1);
#pragma unroll
    for (int ct = 0; ct < 16; ct++) {
        if (ct + 2 < 16) loadK(kb[(ct + 2) % 3], ct + 2);
        tileS(kb[ct % 3], ct);
    }
    __syncthreads();

    // ---- softmax: wave handles rows wid*8 .. wid*8+7 ----
#pragma unroll 1
    for (int r8 = 0; r8 < 8; r8++) {
        int q = wid * 8 + r8;
        short8_t p0 = *(const short8_t*)&ps[swz8(q, lane * 16)];
        short8_t p1 = *(const short8_t*)&ps[swz8(q, lane * 16 + 8)];
        float v[16];
        b2f8(p0, v); b2f8(p1, v + 8);
        float m = v[0];
#pragma unroll
        for (int i = 1; i < 16; i++) m = fmaxf(m, v[i]);
#pragma unroll
        for (int o = 1; o < 64; o <<= 1) m = fmaxf(m, __shfl_xor(m, o));
        float s = 0.f;
#pragma unroll
        for (int i = 0; i < 16; i++) { v[i] = __expf(v[i] - m); s += v[i]; }
#pragma unroll
        for (int o = 1; o < 64; o <<= 1) s += __shfl_xor(s, o);
        bool mq = mbg[bcq + tq0 + q] != 0.0f;
        float inv = mq ? 0.f : (1.f / s);   // masked q-row => p=0 (ref nan_to_num)
        short8_t o0, o1;
#pragma unroll
        for (int i = 0; i < 8; i++) { o0[i] = f2bt(v[i] * inv); o1[i] = f2bt(v[i + 8] * inv); }
        *(short8_t*)&ps[swz8(q, lane * 16)] = o0;
        *(short8_t*)&ps[swz8(q, lane * 16 + 8)] = o1;
    }
    __syncthreads();

    // ---- phase 2: O = P V (wave covers d-slice wid*64, all 32 rows) ----
    const int dh = wid * 64;
    float4_t oacc[2][4];
#pragma unroll
    for (int mt = 0; mt < 2; mt++)
#pragma unroll
        for (int nt = 0; nt < 4; nt++) oacc[mt][nt] = (float4_t){0.f, 0.f, 0.f, 0.f};

    short8_t vb[3][4], ab[3][2];
    auto loadV = [&](short8_t* dst, int s) {
        const short* vp = vt + kvbase + (long)(dh + row) * 1024 + s * 32 + quad * 8;
#pragma unroll
        for (int nt = 0; nt < 4; nt++) dst[nt] = *(const short8_t*)(vp + (long)nt * 16 * 1024);
    };
    auto loadP = [&](short8_t* dst, int s) {
#pragma unroll
        for (int mt = 0; mt < 2; mt++)
            dst[mt] = *(const short8_t*)&ps[swz8(mt * 16 + row, s * 32 + quad * 8)];
    };
    loadV(vb[0], 0); loadP(ab[0], 0);
    loadV(vb[1], 1); loadP(ab[1], 1);
#pragma unroll
    for (int s = 0; s < 32; s++) {
        if (s + 2 < 32) { loadV(vb[(s + 2) % 3], s + 2); loadP(ab[(s + 2) % 3], s + 2); }
#pragma unroll
        for (int mt = 0; mt < 2; mt++)
#pragma unroll
            for (int nt = 0; nt < 4; nt++)
                oacc[mt][nt] = __builtin_amdgcn_mfma_f32_16x16x32_bf16(
                    ab[s % 3][mt], vb[s % 3][nt], oacc[mt][nt], 0, 0, 0);
    }

    __syncthreads();                       // all waves done reading ps
    float* os = (float*)ps;                // reuse as O fp32 [32][260]
#pragma unroll
    for (int mt = 0; mt < 2; mt++)
#pragma unroll
        for (int nt = 0; nt < 4; nt++) {
            int d = dh + nt * 16 + row;
#pragma unroll
            for (int r = 0; r < 4; r++)
                os[(mt * 16 + quad * 4 + r) * 260 + d] = oacc[mt][nt][r];
        }
    __syncthreads();

    // ---- epilogue: y = x + ls_gamma*o ; LayerNorm(D=256) ; fp32 out ----
    const int q = tid >> 3, d0 = (tid & 7) * 32;
    const long xoff = (((long)b * 1024 + tq0 + q) * 16 + c) * 256 + d0;
    float y[32];
    float s1 = 0.f, s2 = 0.f;
#pragma unroll
    for (int i = 0; i < 32; i += 8) {
        float8_t xv = *(const float8_t*)(x + xoff + i);
        float8_t g8 = *(const float8_t*)(lsg + d0 + i);
#pragma unroll
        for (int j = 0; j < 8; j++) {
            float yy = xv[j] + g8[j] * os[q * 260 + d0 + i + j];
            y[i + j] = yy; s1 += yy; s2 += yy * yy;
        }
    }
#pragma unroll
    for (int o = 1; o < 8; o <<= 1) { s1 += __shfl_xor(s1, o); s2 += __shfl_xor(s2, o); }
    float mu = s1 * (1.f / 256.f);
    float var = s2 * (1.f / 256.f) - mu * mu;
    float rstd = rsqrtf(var + 1e-5f);
#pragma unroll
    for (int i = 0; i < 32; i += 8) {
        float8_t g8 = *(const float8_t*)(lng + d0 + i);
        float8_t b8 = *(const float8_t*)(lnb + d0 + i);
        float8_t o8;
#pragma unroll
        for (int j = 0; j < 8; j++) o8[j] = (y[i + j] - mu) * rstd * g8[j] + b8[j];
        *(float8_t*)(out + xoff + i) = o8;
    }
}

// ---------------------------------------------------------------------------
extern "C" void kernel_launch(void* const* d_in, const int* in_sizes, int n_in,
                              void* d_out, int out_size, void* d_ws, size_t ws_size,
                              hipStream_t stream) {
    const float* x = (const float*)d_in[0];
    const unsigned char* xmask = (const unsigned char*)d_in[1];
    const int* pos = (const int*)d_in[2];
    const float* pe = (const float*)d_in[3];
    const float* wq = (const float*)d_in[4];
    const float* bq = (const float*)d_in[5];
    const float* wk = (const float*)d_in[6];
    const float* bk = (const float*)d_in[7];
    const float* wv = (const float*)d_in[8];
    const float* bv = (const float*)d_in[9];
    const float* lng = (const float*)d_in[10];
    const float* lnb = (const float*)d_in[11];
    const float* lsg = (const float*)d_in[12];
    float* out = (float*)d_out;

    short* qw = (short*)d_ws;              // 32MB
    short* kw = qw + 16777216;             // 32MB
    short* vtw = kw + 16777216;            // 32MB
    short* wbw = vtw + 16777216;           // 384KB
    float* mbg = (float*)(wbw + 196608);   // 256KB mask bias

    prep_kernel<<<448, 256, 0, stream>>>(wq, wk, wv, xmask, wbw, mbg);
    qkv_mfma_kernel<<<1024, 256, 0, stream>>>(x, pos, pe, wbw, bq, bk, bv,
                                              qw, kw, vtw);
    attn_kernel<<<2048, 256, 0, stream>>>(qw, kw, vtw, mbg, x, lsg, lng, lnb, out);
}